// Round 6
// baseline (54.862 us; speedup 1.0000x reference)
//
#include <hip/hip_runtime.h>
#include <cfloat>

typedef float f32x2 __attribute__((ext_vector_type(2)));

// Problem constants (from reference setup_inputs)
constexpr int B = 4;
constexpr int N = 8192;          // points per cloud
constexpr int Q = 4;             // query points per thread
constexpr int BLK = 256;         // threads per block
constexpr int QPB = Q * BLK;     // 1024 queries per block
constexpr int NQG = N / QPB;     // 8 query groups per batch
constexpr int SQG = 2 * B * NQG; // 64 (dir,b,qg) query groups
constexpr int NSEG = 2 * B;      // 8 (dir,b) segments
constexpr int PAIRS_PER_ARR = B * N / 2;   // 16384 point-pairs per array

// Pack targets for v_pk_fma_f32 with wave-uniform (scalar-path) loads:
//   tp[arr][k][0] = (-2x0, -2x1, -2y0, -2y1)
//   tp[arr][k][1] = (-2z0, -2z1, |g0|^2, |g1|^2)     arr: 0=pred, 1=gt
__global__ __launch_bounds__(256) void transform_pts(
        const float* __restrict__ pred, const float* __restrict__ gt,
        float4* __restrict__ tp) {
    int pg  = blockIdx.x * 256 + threadIdx.x;    // [0, 2*PAIRS_PER_ARR)
    int arr = pg / PAIRS_PER_ARR;
    int k   = pg % PAIRS_PER_ARR;
    const float* src = (arr ? gt : pred) + (size_t)k * 6;
    float x0 = src[0], y0 = src[1], z0 = src[2];
    float x1 = src[3], y1 = src[4], z1 = src[5];
    float4* dst = tp + (size_t)pg * 2;
    dst[0] = make_float4(-2.f * x0, -2.f * x1, -2.f * y0, -2.f * y1);
    dst[1] = make_float4(-2.f * z0, -2.f * z1,
                         fmaf(x0, x0, fmaf(y0, y0, z0 * z0)),
                         fmaf(x1, x1, fmaf(y1, y1, z1 * z1)));
}

// part[sqg][ch][QPB] partial mins; no LDS, no atomics, no barriers.
template <int NCH>
__global__ __launch_bounds__(BLK) void chamfer_main(
        const float* __restrict__ pred, const float* __restrict__ gt,
        const float4* __restrict__ tp, float* __restrict__ part) {
    constexpr int CHUNK = N / NCH;
    constexpr int PAIRS = CHUNK / 2;
    int bid = blockIdx.x;
    int sqg = bid / NCH;              // (dir,b,qg) group
    int ch  = bid % NCH;
    int dir = sqg / (B * NQG);
    int rem = sqg % (B * NQG);
    int b   = rem / NQG;
    int qg  = rem % NQG;

    const float* qry = dir ? gt : pred;
    // target array is the opposite cloud: dir=0 -> gt (arr 1), dir=1 -> pred (arr 0)
    const float4* tbase = tp +
        ((size_t)(dir ^ 1) * PAIRS_PER_ARR + (size_t)b * (N / 2) +
         (size_t)ch * PAIRS) * 2;

    // Q query points per thread; coords duplicated into both packed halves.
    f32x2 qx[Q], qy[Q], qz[Q];
    float pn[Q], mn[Q];
    const float* qbase = qry + (size_t)b * N * 3 + (size_t)qg * QPB * 3;
#pragma unroll
    for (int q = 0; q < Q; ++q) {
        int qi = threadIdx.x + q * BLK;
        float px = qbase[qi * 3 + 0];
        float py = qbase[qi * 3 + 1];
        float pz = qbase[qi * 3 + 2];
        qx[q] = (f32x2){px, px};
        qy[q] = (f32x2){py, py};
        qz[q] = (f32x2){pz, pz};
        pn[q] = fmaf(px, px, fmaf(py, py, pz * pz));
        mn[q] = FLT_MAX;
    }

    // Inner loop: targets come in via uniform loads (scalar path / broadcast),
    // zero LDS traffic. 3 pk_fma + 1 min3 per query per 2 targets.
#pragma unroll 4
    for (int j2 = 0; j2 < PAIRS; ++j2) {
        float4 A  = tbase[2 * j2];
        float4 Bv = tbase[2 * j2 + 1];
        f32x2 xp = (f32x2){A.x,  A.y};
        f32x2 yp = (f32x2){A.z,  A.w};
        f32x2 zp = (f32x2){Bv.x, Bv.y};
        f32x2 wp = (f32x2){Bv.z, Bv.w};
#pragma unroll
        for (int q = 0; q < Q; ++q) {
            f32x2 t = __builtin_elementwise_fma(qx[q], xp,
                      __builtin_elementwise_fma(qy[q], yp,
                      __builtin_elementwise_fma(qz[q], zp, wp)));
            mn[q] = fminf(fminf(t.x, t.y), mn[q]);   // -> v_min3_f32
        }
    }

    // Plain coalesced stores to this block's unique slab.
    float* po = part + ((size_t)sqg * NCH + ch) * QPB;
#pragma unroll
    for (int q = 0; q < Q; ++q)
        po[threadIdx.x + q * BLK] = fmaxf(mn[q] + pn[q], 0.f);
}

// 256 blocks; each handles 256 queries of one sqg group: min over NCH chunks,
// then block-level sum & max partials.
template <int NCH>
__global__ __launch_bounds__(256) void reduce1(
        const float* __restrict__ part, float* __restrict__ bsum,
        float* __restrict__ bmax) {
    constexpr int SUBS = QPB / 256;   // blocks per sqg group
    int sqg = blockIdx.x / SUBS;
    int qi  = (blockIdx.x % SUBS) * 256 + threadIdx.x;
    const float* base = part + (size_t)sqg * NCH * QPB + qi;
    float v = FLT_MAX;
#pragma unroll
    for (int ch = 0; ch < NCH; ++ch)
        v = fminf(v, base[(size_t)ch * QPB]);   // coalesced across threads
    __shared__ float ssum[256], smax[256];
    ssum[threadIdx.x] = v;
    smax[threadIdx.x] = v;
    __syncthreads();
    for (int st = 128; st > 0; st >>= 1) {
        if (threadIdx.x < st) {
            ssum[threadIdx.x] += ssum[threadIdx.x + st];
            smax[threadIdx.x] = fmaxf(smax[threadIdx.x], smax[threadIdx.x + st]);
        }
        __syncthreads();
    }
    if (threadIdx.x == 0) {
        bsum[blockIdx.x] = ssum[0];
        bmax[blockIdx.x] = smax[0];
    }
}

// Combine 256 block partials. Blocks [seg*32, seg*32+32) belong to segment seg.
__global__ __launch_bounds__(256) void final_combine(
        const float* __restrict__ bsum, const float* __restrict__ bmax,
        float* __restrict__ out) {
    int t = threadIdx.x;
    __shared__ float ss[256], sm[256];
    ss[t] = bsum[t];
    sm[t] = bmax[t];
    __syncthreads();
    for (int st = 128; st > 0; st >>= 1) {
        if (t < st) ss[t] += ss[t + st];
        __syncthreads();
    }
    for (int st = 16; st > 0; st >>= 1) {
        if ((t & 31) < st) sm[t] = fmaxf(sm[t], sm[t + st]);
        __syncthreads();
    }
    if (t == 0) {
        float hsum = 0.f;
#pragma unroll
        for (int k = 0; k < NSEG; ++k) hsum += sm[k * 32];
        out[0] = ss[0] / (float)(B * N);   // chamfer
        out[1] = hsum / (float)B;          // hausdorff
    }
}

template <int NCH>
static void launch_all(const float* pred, const float* gt, void* d_ws,
                       float* out, hipStream_t stream) {
    float* part = (float*)d_ws;
    float4* tp  = (float4*)(part + (size_t)SQG * NCH * QPB);
    float* bsum = (float*)(tp + (size_t)2 * PAIRS_PER_ARR * 2);
    float* bmax = bsum + 256;
    transform_pts<<<2 * PAIRS_PER_ARR / 256, 256, 0, stream>>>(pred, gt, tp);
    chamfer_main<NCH><<<SQG * NCH, BLK, 0, stream>>>(pred, gt, tp, part);
    reduce1<NCH><<<256, 256, 0, stream>>>(part, bsum, bmax);
    final_combine<<<1, 256, 0, stream>>>(bsum, bmax, out);
}

extern "C" void kernel_launch(void* const* d_in, const int* in_sizes, int n_in,
                              void* d_out, int out_size, void* d_ws, size_t ws_size,
                              hipStream_t stream) {
    const float* pred = (const float*)d_in[0];
    const float* gt   = (const float*)d_in[1];
    float* out = (float*)d_out;

    auto need = [](int nch) {
        return (size_t)SQG * nch * QPB * sizeof(float)        // part slab
             + (size_t)2 * PAIRS_PER_ARR * 2 * sizeof(float4) // tp (1 MB)
             + 512 * sizeof(float);                           // bsum/bmax
    };
    if (ws_size >= need(32))      launch_all<32>(pred, gt, d_ws, out, stream);
    else if (ws_size >= need(16)) launch_all<16>(pred, gt, d_ws, out, stream);
    else if (ws_size >= need(8))  launch_all<8>(pred, gt, d_ws, out, stream);
    else                          launch_all<4>(pred, gt, d_ws, out, stream);
}